// Round 1
// baseline (408.067 us; speedup 1.0000x reference)
//
#include <hip/hip_runtime.h>
#include <math.h>

#define TOKENS   8192
#define HIDDEN   7168
#define NEXPERT  256
#define NGROUP   8
#define TOPKG    4
#define TOPK     8
#define SCALE    2.5f

// GEMM: 128 tokens x 128 experts per block, BK=32, split-K 4 via atomicAdd
// into d_out (R3-proven: atomic accumulation to d_out = ~16 MB HBM writes).
// R7 (this round): W pre-split into fp16 hi/lo ONCE per launch (wsplit_kernel,
// 7.34 MB in d_ws, stored as pre-swizzled per-tile LDS images) -> B staging
// becomes global_load_lds DMA (no cvt VALU, no ds_write, no VGPR round-trip).
// A+B LDS layouts unpadded + XOR-swizzled (byte ^= (row&7)<<4): conflict-free
// b128 frag reads, A staged with ds_write_b128. LDS 72->64 KB, 2 blocks/CU.
#define BM 128
#define BN 128
#define BK 32
#define KSPLIT 4
#define KPB (HIDDEN / KSPLIT)   // 1792
#define NT  (KPB / BK)          // 56
#define TILE_BYTES 16384        // 128 rows x 4 k-octets x (hi8+lo8 fp16)

// LDS tile layout (A and B identical, and identical to the d_ws W-image):
//   halves: row r (0..127), k-octet o (0..3), hi/lo hl, j (0..7)
//   byte = (r*128 + o*32 + hl*16 + j*2) ^ ((r&7)<<4)
// Frag read (lane fr=lane&15, quad=lane>>4): row=wbase+f*16+fr -> row&7=fr&7,
// start banks (quad*8 + (fr&7)*4)%32 -> 2-way max (free, m136). A-staging
// b128 writes: rows 0..15 x octets 0..3 per wave -> 2-way max. B is DMA'd
// linearly from the pre-swizzled global image (m173 pattern).

typedef _Float16 half8 __attribute__((ext_vector_type(8)));
typedef float    floatx4 __attribute__((ext_vector_type(4)));

// fp32x8 -> fp16 hi/lo split. RNE, identical bits to the proven prior path:
// h = (fp16)v; l = (fp16)(v - h). Dropped term in the 3-product MFMA sum is
// l*l' ~ 2^-22 relative -> bit-stable through routing (measured absmax 0.0).
__device__ __forceinline__ void cvt8(const float4 a, const float4 b,
                                     half8& h, half8& l) {
    h[0] = (_Float16)a.x; h[1] = (_Float16)a.y;
    h[2] = (_Float16)a.z; h[3] = (_Float16)a.w;
    h[4] = (_Float16)b.x; h[5] = (_Float16)b.y;
    h[6] = (_Float16)b.z; h[7] = (_Float16)b.w;
    l[0] = (_Float16)(a.x - (float)h[0]); l[1] = (_Float16)(a.y - (float)h[1]);
    l[2] = (_Float16)(a.z - (float)h[2]); l[3] = (_Float16)(a.w - (float)h[3]);
    l[4] = (_Float16)(b.x - (float)h[4]); l[5] = (_Float16)(b.y - (float)h[5]);
    l[6] = (_Float16)(b.z - (float)h[6]); l[7] = (_Float16)(b.w - (float)h[7]);
}

// async global->LDS, 16 B/lane. LDS dest is wave-uniform base + lane*16 (m104);
// per-lane global src carries the layout (pre-swizzled image -> linear copy).
__device__ __forceinline__ void lds_dma16(const char* g, char* l) {
    __builtin_amdgcn_global_load_lds(
        (const __attribute__((address_space(1))) void*)g,
        (__attribute__((address_space(3))) void*)l, 16, 0, 0);
}

// ---------------------------------------------------------------------------
// zero d_out (poisoned 0xAA each iteration; atomic accumulation needs 0 init)
// ---------------------------------------------------------------------------
__global__ __launch_bounds__(256) void zero_kernel(float* __restrict__ O) {
    const int i = blockIdx.x * 256 + threadIdx.x;
    *(float4*)&O[(size_t)i * 4] = float4{0.f, 0.f, 0.f, 0.f};
}

// ---------------------------------------------------------------------------
// W pre-split: fp32 [256,7168] -> fp16 hi/lo LDS-image tiles in d_ws.
// Tile (nb,kz,t) is the exact 16 KB the GEMM DMA-copies into LDS.
// One block per expert, 896 threads, one k-octet (8 values, 32 B) per thread.
// Cost: 7.34 MB R + 7.34 MB W ~= 3 us once per launch; kills the 64x-redundant
// per-M-block W conversion (half of gate_gemm's VALUBusy).
// ---------------------------------------------------------------------------
__global__ __launch_bounds__(896) void wsplit_kernel(
    const float* __restrict__ W, char* __restrict__ WS)
{
    const int e  = blockIdx.x;          // expert 0..255
    const int og = threadIdx.x;         // octet-in-expert 0..895
    const float4 a = *(const float4*)&W[(size_t)e * HIDDEN + og * 8];
    const float4 b = *(const float4*)&W[(size_t)e * HIDDEN + og * 8 + 4];
    half8 h, l;
    cvt8(a, b, h, l);

    const int kz  = og / 224;           // k-split   0..3
    const int tt  = (og % 224) >> 2;    // k-tile    0..55
    const int oc  = og & 3;             // octet     0..3
    const int row = e & 127, nb = e >> 7;
    char* base = WS + (size_t)((nb * KSPLIT + kz) * NT + tt) * TILE_BYTES;
    const int b0 = (row * 128 + oc * 32) ^ ((row & 7) << 4);
    *(half8*)(base + b0)        = h;
    *(half8*)(base + (b0 ^ 16)) = l;
}

// ---------------------------------------------------------------------------
// Gate GEMM via fp16-split 3-product MFMA (bit-exact through routing):
//   x = xh + xl (fp16 RNE), logit = sum xl*wh + xh*wl + xh*wh  (fp32 acc,
//   same product order and K order as the proven kernel).
// Double-buffered LDS, one barrier per K-tile. Per tile, after the barrier:
// A global loads issued FIRST, then B DMA -> the A-cvt's wait is a counted
// vmcnt(4) leaving the DMA in flight until the next barrier (no vmcnt(0)
// drain on the critical path except the barrier itself).
// ---------------------------------------------------------------------------
__global__ __launch_bounds__(256, 2) void gate_gemm_kernel(
    const float* __restrict__ X, const char* __restrict__ WS,
    float* __restrict__ OUT)
{
    __shared__ __attribute__((aligned(128))) char Ab[2][TILE_BYTES];  // 32 KB
    __shared__ __attribute__((aligned(128))) char Bb[2][TILE_BYTES];  // 32 KB

    const int tid = threadIdx.x;
    const int nb  = blockIdx.x * BN;
    const int mb  = blockIdx.y * BM;
    const int kb  = blockIdx.z * KPB;

    // A staging map: thread -> (row = (tid>>2) + 64*pass, octet = tid&3).
    // Loads: 2 float4 per pass, 32 consecutive rows x 128 B per wave-instr
    // (fully coalesced). Writes: 2 x ds_write_b128 per pass.
    const int arow = tid >> 2;          // 0..63
    const int aoct = tid & 3;
    const float* Aptr = X + (size_t)(mb + arow) * HIDDEN + kb + aoct * 8;
    const int ab0 = (arow * 128 + aoct * 32) ^ ((arow & 7) << 4);

    const char* Wimg =
        WS + (size_t)((blockIdx.x * KSPLIT + blockIdx.z) * NT) * TILE_BYTES;

    const int lane = tid & 63, wave = tid >> 6;
    const int wm = (wave >> 1) * 64, wn = (wave & 1) * 64;
    const int fr = lane & 15, quad = lane >> 4;

    // prologue: stage tile 0
    {
        const char* src = Wimg + wave * 4096 + lane * 16;
        char* dst = &Bb[0][wave * 4096];
#pragma unroll
        for (int c = 0; c < 4; c++)
            lds_dma16(src + c * 1024, dst + c * 1024);

#pragma unroll
        for (int p = 0; p < 2; p++) {
            const float4 a = *(const float4*)(Aptr + (size_t)p * 64 * HIDDEN);
            const float4 b = *(const float4*)(Aptr + (size_t)p * 64 * HIDDEN + 4);
            half8 h, l;
            cvt8(a, b, h, l);
            const int off = ab0 + p * 8192;
            *(half8*)&Ab[0][off]      = h;
            *(half8*)&Ab[0][off ^ 16] = l;
        }
    }

    floatx4 acc[4][4];
#pragma unroll
    for (int i = 0; i < 4; i++)
#pragma unroll
        for (int j = 0; j < 4; j++) acc[i][j] = floatx4{0.f, 0.f, 0.f, 0.f};

    for (int t = 0; t < NT; t++) {
        __syncthreads();   // buf[t&1] staged (lgkmcnt for A writes, vmcnt for
                           // B DMA drained by the compiler's barrier waitcnt)

        const int cur = t & 1, nxt = (t + 1) & 1;
        float4 na0, nb0, na1, nb1;
        if (t + 1 < NT) {
            // A global loads first (consumed by cvt after MFMA -> hidden)
            const float* ap = Aptr + (t + 1) * BK;
            na0 = *(const float4*)(ap);
            nb0 = *(const float4*)(ap + 4);
            na1 = *(const float4*)(ap + (size_t)64 * HIDDEN);
            nb1 = *(const float4*)(ap + (size_t)64 * HIDDEN + 4);
            // B DMA second: stays in flight across the cvt's counted wait,
            // drained only at the next barrier (whole MFMA phase of cover)
            const char* src = Wimg + (size_t)(t + 1) * TILE_BYTES
                            + wave * 4096 + lane * 16;
            char* dst = &Bb[nxt][wave * 4096];
#pragma unroll
            for (int c = 0; c < 4; c++)
                lds_dma16(src + c * 1024, dst + c * 1024);
        }

        const char* Ac = Ab[cur];
        const char* Bc = Bb[cur];

        half8 ah[4], al[4];
#pragma unroll
        for (int i = 0; i < 4; i++) {
            const int r = wm + i * 16 + fr;
            const int o = (r * 128 + quad * 32) ^ ((r & 7) << 4);
            ah[i] = *(const half8*)&Ac[o];
            al[i] = *(const half8*)&Ac[o ^ 16];
        }
#pragma unroll
        for (int j = 0; j < 4; j++) {
            const int r = wn + j * 16 + fr;
            const int o = (r * 128 + quad * 32) ^ ((r & 7) << 4);
            const half8 bh = *(const half8*)&Bc[o];
            const half8 bl = *(const half8*)&Bc[o ^ 16];
#pragma unroll
            for (int i = 0; i < 4; i++) {
                acc[i][j] = __builtin_amdgcn_mfma_f32_16x16x32_f16(
                    al[i], bh, acc[i][j], 0, 0, 0);
                acc[i][j] = __builtin_amdgcn_mfma_f32_16x16x32_f16(
                    ah[i], bl, acc[i][j], 0, 0, 0);
                acc[i][j] = __builtin_amdgcn_mfma_f32_16x16x32_f16(
                    ah[i], bh, acc[i][j], 0, 0, 0);
            }
        }

        // stage next A tile into the other buffer (overlaps this tile's MFMA)
        if (t + 1 < NT) {
            half8 h, l;
            cvt8(na0, nb0, h, l);
            *(half8*)&Ab[nxt][ab0]      = h;
            *(half8*)&Ab[nxt][ab0 ^ 16] = l;
            cvt8(na1, nb1, h, l);
            *(half8*)&Ab[nxt][(ab0 + 8192)]      = h;
            *(half8*)&Ab[nxt][(ab0 + 8192) ^ 16] = l;
        }
    }

    // epilogue: D row = token (quad*4+reg), col = expert (lane&15);
    // split-K accumulation via atomicAdd (R3-measured: ~16 MB HBM writes)
#pragma unroll
    for (int i = 0; i < 4; i++)
#pragma unroll
        for (int j = 0; j < 4; j++) {
            const int col = nb + wn + j * 16 + fr;
#pragma unroll
            for (int r = 0; r < 4; r++) {
                const int row = mb + wm + i * 16 + quad * 4 + r;
                atomicAdd(&OUT[(size_t)row * NEXPERT + col], acc[i][j][r]);
            }
        }
}

// ---------------------------------------------------------------------------
// Routing: one wave per token, in-place on d_out (logits -> gate weights).
// Sigmoid fused; exact jax semantics incl. lowest-index tie-breaks.
// ---------------------------------------------------------------------------
__global__ __launch_bounds__(256) void route_kernel(
    float* __restrict__ S, const float* __restrict__ bias)
{
    const int lane = threadIdx.x & 63;
    const int wave = threadIdx.x >> 6;
    const int t    = blockIdx.x * 4 + wave;

    const float4 lg4 = *(const float4*)&S[(size_t)t * NEXPERT + lane * 4];
    const float4 b4  = *(const float4*)&bias[lane * 4];
    float sc[4];
    sc[0] = 1.0f / (1.0f + expf(-lg4.x));
    sc[1] = 1.0f / (1.0f + expf(-lg4.y));
    sc[2] = 1.0f / (1.0f + expf(-lg4.z));
    sc[3] = 1.0f / (1.0f + expf(-lg4.w));
    float swb[4] = { sc[0] + b4.x, sc[1] + b4.y, sc[2] + b4.z, sc[3] + b4.w };

    // per-lane top-2 of 4
    float m1 = -INFINITY, m2 = -INFINITY;
#pragma unroll
    for (int j = 0; j < 4; j++) {
        const float v = swb[j];
        if (v > m1)      { m2 = m1; m1 = v; }
        else if (v > m2) { m2 = v; }
    }
    // merge across the 8 lanes of my group
#pragma unroll
    for (int s = 1; s < 8; s <<= 1) {
        const float o1 = __shfl_xor(m1, s, 64);
        const float o2 = __shfl_xor(m2, s, 64);
        const float hi = fmaxf(m1, o1);
        const float lo = fminf(m1, o1);
        m2 = fmaxf(lo, fmaxf(m2, o2));
        m1 = hi;
    }
    const float gs = m1 + m2;

    // top-4 groups by rank (tie -> lower group index)
    float gsc[NGROUP];
#pragma unroll
    for (int g = 0; g < NGROUP; g++) gsc[g] = __shfl(gs, g * 8, 64);
    const int myg = lane >> 3;
    int rank = 0;
#pragma unroll
    for (int g = 0; g < NGROUP; g++)
        rank += (gsc[g] > gs) || (gsc[g] == gs && g < myg);
    const bool kept = (rank < TOPKG);

    float v[4];
#pragma unroll
    for (int j = 0; j < 4; j++) v[j] = kept ? swb[j] : 0.0f;

    // top-8 experts: 8 rounds of wave argmax (lowest idx on ties)
    float sum = 0.0f;
    int selmask = 0;
    for (int r = 0; r < TOPK; r++) {
        float bv = -INFINITY;
        int   bi = 0x7fffffff;
#pragma unroll
        for (int j = 0; j < 4; j++) {
            const bool avail = ((selmask >> j) & 1) == 0;
            if (avail && v[j] > bv) { bv = v[j]; bi = lane * 4 + j; }
        }
#pragma unroll
        for (int s = 1; s < 64; s <<= 1) {
            const float ov = __shfl_xor(bv, s, 64);
            const int   oi = __shfl_xor(bi, s, 64);
            if (ov > bv || (ov == bv && oi < bi)) { bv = ov; bi = oi; }
        }
        const int wl = bi >> 2, wj = bi & 3;
        const float mysc = (wj == 0) ? sc[0] : (wj == 1) ? sc[1]
                         : (wj == 2) ? sc[2] : sc[3];
        sum += __shfl(mysc, wl, 64);
        if (lane == wl) selmask |= (1 << wj);
    }

    const float rcp = SCALE / (sum + 1e-20f);
    float4 o;
    o.x = (selmask & 1) ? sc[0] * rcp : 0.0f;
    o.y = (selmask & 2) ? sc[1] * rcp : 0.0f;
    o.z = (selmask & 4) ? sc[2] * rcp : 0.0f;
    o.w = (selmask & 8) ? sc[3] * rcp : 0.0f;
    *(float4*)&S[(size_t)t * NEXPERT + lane * 4] = o;
}

extern "C" void kernel_launch(void* const* d_in, const int* in_sizes, int n_in,
                              void* d_out, int out_size, void* d_ws, size_t ws_size,
                              hipStream_t stream) {
    const float* X    = (const float*)d_in[0];   // [8192, 7168]
    const float* W    = (const float*)d_in[1];   // [256, 7168]
    const float* bias = (const float*)d_in[2];   // [256]
    float* out = (float*)d_out;                  // [8192, 256]
    // d_ws: 448 tiles x 16 KB = 7,340,032 B of pre-split W images (ws_size is
    // ~hundreds of MB per the harness poison fill; fully rewritten each launch
    // so the 0xAA poison is harmless).
    char* ws = (char*)d_ws; (void)ws_size;

    zero_kernel<<<(TOKENS * NEXPERT / 4) / 256, 256, 0, stream>>>(out);
    wsplit_kernel<<<NEXPERT, 896, 0, stream>>>(W, ws);
    dim3 ggrid(NEXPERT / BN, TOKENS / BM, KSPLIT);   // (2, 64, 4) = 512 blocks
    gate_gemm_kernel<<<ggrid, 256, 0, stream>>>(X, ws, out);
    route_kernel<<<TOKENS / 4, 256, 0, stream>>>(out, bias);
}

// Round 2
// 385.163 us; speedup vs baseline: 1.0595x; 1.0595x over previous
//
#include <hip/hip_runtime.h>
#include <math.h>

#define TOKENS   8192
#define HIDDEN   7168
#define NEXPERT  256
#define NGROUP   8
#define TOPKG    4
#define TOPK     8
#define SCALE    2.5f

// GEMM: 128 tokens x 128 experts per block, BK=32, split-K 4 via atomicAdd
// into d_out (R3-proven). LDS double-buffered 2x(A 18K + B 18K) = 72 KB,
// 2 blocks/CU, grid 512. R6 structure restored exactly (R7 post-mortem:
// global_load_lds forces vmcnt(0) drain at every __syncthreads -> exposed
// B-fetch latency, gemm 141->158. Register staging keeps loads un-drained
// at the barrier; they wait at first use, AFTER the MFMA phase).
// R8 keeps wsplit: W pre-split fp16 hi/lo ONCE (7.34 MB in d_ws, packed
// 32B (hi8|lo8) per (row,k-octet)) -> B staging = 2x32B loads + 4x
// ds_write_b128 per thread, ZERO cvt VALU (was ~half the staging VALU and
// sat on the post-MFMA critical path).
#define BM 128
#define BN 128
#define BK 32
#define KSPLIT 4
#define KPB (HIDDEN / KSPLIT)   // 1792
#define NT  (KPB / BK)          // 56
#define TILE_BYTES 16384        // packed W image: 128 rows x 4 octets x 32B

// LDS layout (halves): addr(row,k,hl) = row*72 + (k>>3)*16 + hl*8 + (k&7).
// Row stride 72 halves = 144 B: 16B-aligned b128 frags. Bank analysis (R7):
// wave64 b128 reads have an 8-lanes-per-start-bank hardware floor in ANY
// 16B-aligned layout -> the 7.34M conflict count is structural, not layout.
#define RSTR 72

typedef _Float16 half8 __attribute__((ext_vector_type(8)));
typedef _Float16 half4 __attribute__((ext_vector_type(4)));
typedef float    floatx4 __attribute__((ext_vector_type(4)));

// fp32 -> fp16 hi/lo split, store h4 at octet +0..7, l4 at +8..15
__device__ __forceinline__ void cvt_store(_Float16* __restrict__ H,
                                          int row, int k0, float4 v) {
    half4 h, l;
    h[0] = (_Float16)v.x; h[1] = (_Float16)v.y;
    h[2] = (_Float16)v.z; h[3] = (_Float16)v.w;
    l[0] = (_Float16)(v.x - (float)h[0]);
    l[1] = (_Float16)(v.y - (float)h[1]);
    l[2] = (_Float16)(v.z - (float)h[2]);
    l[3] = (_Float16)(v.w - (float)h[3]);
    const int base = row * RSTR + ((k0 >> 3) << 4) + (k0 & 7);
    *(half4*)&H[base]     = h;
    *(half4*)&H[base + 8] = l;
}

// fp32x8 -> fp16 hi/lo split (same RNE bits as cvt_store; used by wsplit)
__device__ __forceinline__ void cvt8(const float4 a, const float4 b,
                                     half8& h, half8& l) {
    h[0] = (_Float16)a.x; h[1] = (_Float16)a.y;
    h[2] = (_Float16)a.z; h[3] = (_Float16)a.w;
    h[4] = (_Float16)b.x; h[5] = (_Float16)b.y;
    h[6] = (_Float16)b.z; h[7] = (_Float16)b.w;
    l[0] = (_Float16)(a.x - (float)h[0]); l[1] = (_Float16)(a.y - (float)h[1]);
    l[2] = (_Float16)(a.z - (float)h[2]); l[3] = (_Float16)(a.w - (float)h[3]);
    l[4] = (_Float16)(b.x - (float)h[4]); l[5] = (_Float16)(b.y - (float)h[5]);
    l[6] = (_Float16)(b.z - (float)h[6]); l[7] = (_Float16)(b.w - (float)h[7]);
}

// ---------------------------------------------------------------------------
// zero d_out (poisoned 0xAA each iteration; atomic accumulation needs 0 init)
// ---------------------------------------------------------------------------
__global__ __launch_bounds__(256) void zero_kernel(float* __restrict__ O) {
    const int i = blockIdx.x * 256 + threadIdx.x;
    *(float4*)&O[(size_t)i * 4] = float4{0.f, 0.f, 0.f, 0.f};
}

// ---------------------------------------------------------------------------
// W pre-split: fp32 [256,7168] -> packed fp16 hi/lo tiles in d_ws.
// Tile (nb,kz,t): 128 rows x 4 octets x (hi8|lo8) = 16 KB, octet-contiguous
// so GEMM B-staging is 2 coalesced 32B reads + 4 ds_write_b128 per thread.
// One block per expert, 896 threads, one k-octet each. ~3 us once per launch;
// kills the 64x-redundant per-M-block W conversion.
// ---------------------------------------------------------------------------
__global__ __launch_bounds__(896) void wsplit_kernel(
    const float* __restrict__ W, char* __restrict__ WS)
{
    const int e  = blockIdx.x;          // expert 0..255
    const int og = threadIdx.x;         // octet-in-expert 0..895
    const float4 a = *(const float4*)&W[(size_t)e * HIDDEN + og * 8];
    const float4 b = *(const float4*)&W[(size_t)e * HIDDEN + og * 8 + 4];
    half8 h, l;
    cvt8(a, b, h, l);

    const int kz  = og / 224;           // k-split   0..3  (KPB/8 = 224 octets)
    const int tt  = (og % 224) >> 2;    // k-tile    0..55
    const int oc  = og & 3;             // octet     0..3
    const int row = e & 127, nb = e >> 7;
    char* p = WS + (size_t)((nb * KSPLIT + kz) * NT + tt) * TILE_BYTES
            + (row * 4 + oc) * 32;
    *(half8*)p        = h;
    *(half8*)(p + 16) = l;
}

// ---------------------------------------------------------------------------
// Gate GEMM via fp16-split 3-product MFMA (bit-exact through routing):
//   x = xh + xl (fp16 RNE), logit = sum xl*wh + xh*wl + xh*wh  (fp32 acc,
//   same product order and K order as the proven R6 kernel).
// Double-buffered LDS, one barrier per K-tile. All next-tile global loads
// (A fp32 + B fp16-image) issued BEFORE the barrier into VGPRs -> no vmcnt
// drain at the barrier; the loads complete under barrier + frag reads + 48
// MFMA and are consumed in the post-MFMA store phase.
// ---------------------------------------------------------------------------
__global__ __launch_bounds__(256, 2) void gate_gemm_kernel(
    const float* __restrict__ X, const char* __restrict__ WS,
    float* __restrict__ OUT)
{
    __shared__ _Float16 Ab[2][BM * RSTR];   // 2 x 18 KB
    __shared__ _Float16 Bb[2][BN * RSTR];   // 2 x 18 KB  -> 72 KB total

    const int tid = threadIdx.x;
    const int nb  = blockIdx.x * BN;
    const int mb  = blockIdx.y * BM;
    const int kb  = blockIdx.z * KPB;

    // A staging map (R6): thread t takes rows q*32 + (t>>3), k0 = (t&7)*4
    const int srow = tid >> 3;            // 0..31 (+q*32)
    const int sk0  = (tid & 7) * 4;       // 0..28
    const float* Aptr = X + (size_t)(mb + srow) * HIDDEN + kb + sk0;

    // B staging map: pair p = tid + 256*s (s=0,1) -> row = p>>2, oct = p&3;
    // 32B contiguous (hi8|lo8) per pair in the packed W image.
    const char* Wimg =
        WS + (size_t)((blockIdx.x * KSPLIT + blockIdx.z) * NT) * TILE_BYTES;
    const int brow[2] = { tid >> 2, (tid + 256) >> 2 };
    const int boct    = tid & 3;
    const int bbase[2] = { brow[0] * RSTR + boct * 16,
                           brow[1] * RSTR + boct * 16 };

    float4 av[4];
    half8  nh[2], nl[2];
#pragma unroll
    for (int q = 0; q < 4; q++)
        av[q] = *(const float4*)(Aptr + (size_t)(q * 32) * HIDDEN);
#pragma unroll
    for (int s = 0; s < 2; s++) {
        const char* src = Wimg + (tid + 256 * s) * 32;
        nh[s] = *(const half8*)src;
        nl[s] = *(const half8*)(src + 16);
    }
#pragma unroll
    for (int q = 0; q < 4; q++)
        cvt_store(Ab[0], q * 32 + srow, sk0, av[q]);
#pragma unroll
    for (int s = 0; s < 2; s++) {
        *(half8*)&Bb[0][bbase[s]]     = nh[s];
        *(half8*)&Bb[0][bbase[s] + 8] = nl[s];
    }

    // 4 waves as 2x2; wave tile 64m x 64n; 4x4 16x16 frags per wave
    const int lane = tid & 63, wave = tid >> 6;
    const int wm = (wave >> 1) * 64, wn = (wave & 1) * 64;
    const int fr = lane & 15, quad = lane >> 4;

    floatx4 acc[4][4];
#pragma unroll
    for (int i = 0; i < 4; i++)
#pragma unroll
        for (int j = 0; j < 4; j++) acc[i][j] = floatx4{0.f, 0.f, 0.f, 0.f};

    for (int t = 0; t < NT; t++) {
        // issue next tile's global loads first; MFMA below hides latency
        if (t + 1 < NT) {
            const int o = (t + 1) * BK;
#pragma unroll
            for (int q = 0; q < 4; q++)
                av[q] = *(const float4*)(Aptr + o + (size_t)(q * 32) * HIDDEN);
            const char* srcT = Wimg + (size_t)(t + 1) * TILE_BYTES;
#pragma unroll
            for (int s = 0; s < 2; s++) {
                const char* src = srcT + (tid + 256 * s) * 32;
                nh[s] = *(const half8*)src;
                nl[s] = *(const half8*)(src + 16);
            }
        }

        __syncthreads();   // buf[t&1] fully staged; other buf free to write

        const _Float16* __restrict__ Ac = Ab[t & 1];
        const _Float16* __restrict__ Bc = Bb[t & 1];

        half8 ah[4], al[4];
#pragma unroll
        for (int i = 0; i < 4; i++) {
            const int a = (wm + i * 16 + fr) * RSTR + quad * 16;
            ah[i] = *(const half8*)&Ac[a];
            al[i] = *(const half8*)&Ac[a + 8];
        }
#pragma unroll
        for (int j = 0; j < 4; j++) {
            const int b = (wn + j * 16 + fr) * RSTR + quad * 16;
            const half8 bh = *(const half8*)&Bc[b];
            const half8 bl = *(const half8*)&Bc[b + 8];
#pragma unroll
            for (int i = 0; i < 4; i++) {
                acc[i][j] = __builtin_amdgcn_mfma_f32_16x16x32_f16(
                    al[i], bh, acc[i][j], 0, 0, 0);
                acc[i][j] = __builtin_amdgcn_mfma_f32_16x16x32_f16(
                    ah[i], bl, acc[i][j], 0, 0, 0);
                acc[i][j] = __builtin_amdgcn_mfma_f32_16x16x32_f16(
                    ah[i], bh, acc[i][j], 0, 0, 0);
            }
        }

        // stage next tile into the other buffer (overlaps this tile's MFMA)
        if (t + 1 < NT) {
            _Float16* An = Ab[(t + 1) & 1];
            _Float16* Bn = Bb[(t + 1) & 1];
#pragma unroll
            for (int q = 0; q < 4; q++)
                cvt_store(An, q * 32 + srow, sk0, av[q]);
#pragma unroll
            for (int s = 0; s < 2; s++) {
                *(half8*)&Bn[bbase[s]]     = nh[s];
                *(half8*)&Bn[bbase[s] + 8] = nl[s];
            }
        }
    }

    // epilogue: D row = token (quad*4+reg), col = expert (lane&15);
    // split-K accumulation via atomicAdd (R3-measured: ~16 MB HBM writes)
#pragma unroll
    for (int i = 0; i < 4; i++)
#pragma unroll
        for (int j = 0; j < 4; j++) {
            const int col = nb + wn + j * 16 + fr;
#pragma unroll
            for (int r = 0; r < 4; r++) {
                const int row = mb + wm + i * 16 + quad * 4 + r;
                atomicAdd(&OUT[(size_t)row * NEXPERT + col], acc[i][j][r]);
            }
        }
}

// ---------------------------------------------------------------------------
// Routing: one wave per token, in-place on d_out (logits -> gate weights).
// Sigmoid fused; exact jax semantics incl. lowest-index tie-breaks.
// ---------------------------------------------------------------------------
__global__ __launch_bounds__(256) void route_kernel(
    float* __restrict__ S, const float* __restrict__ bias)
{
    const int lane = threadIdx.x & 63;
    const int wave = threadIdx.x >> 6;
    const int t    = blockIdx.x * 4 + wave;

    const float4 lg4 = *(const float4*)&S[(size_t)t * NEXPERT + lane * 4];
    const float4 b4  = *(const float4*)&bias[lane * 4];
    float sc[4];
    sc[0] = 1.0f / (1.0f + expf(-lg4.x));
    sc[1] = 1.0f / (1.0f + expf(-lg4.y));
    sc[2] = 1.0f / (1.0f + expf(-lg4.z));
    sc[3] = 1.0f / (1.0f + expf(-lg4.w));
    float swb[4] = { sc[0] + b4.x, sc[1] + b4.y, sc[2] + b4.z, sc[3] + b4.w };

    // per-lane top-2 of 4
    float m1 = -INFINITY, m2 = -INFINITY;
#pragma unroll
    for (int j = 0; j < 4; j++) {
        const float v = swb[j];
        if (v > m1)      { m2 = m1; m1 = v; }
        else if (v > m2) { m2 = v; }
    }
    // merge across the 8 lanes of my group
#pragma unroll
    for (int s = 1; s < 8; s <<= 1) {
        const float o1 = __shfl_xor(m1, s, 64);
        const float o2 = __shfl_xor(m2, s, 64);
        const float hi = fmaxf(m1, o1);
        const float lo = fminf(m1, o1);
        m2 = fmaxf(lo, fmaxf(m2, o2));
        m1 = hi;
    }
    const float gs = m1 + m2;

    // top-4 groups by rank (tie -> lower group index)
    float gsc[NGROUP];
#pragma unroll
    for (int g = 0; g < NGROUP; g++) gsc[g] = __shfl(gs, g * 8, 64);
    const int myg = lane >> 3;
    int rank = 0;
#pragma unroll
    for (int g = 0; g < NGROUP; g++)
        rank += (gsc[g] > gs) || (gsc[g] == gs && g < myg);
    const bool kept = (rank < TOPKG);

    float v[4];
#pragma unroll
    for (int j = 0; j < 4; j++) v[j] = kept ? swb[j] : 0.0f;

    // top-8 experts: 8 rounds of wave argmax (lowest idx on ties)
    float sum = 0.0f;
    int selmask = 0;
    for (int r = 0; r < TOPK; r++) {
        float bv = -INFINITY;
        int   bi = 0x7fffffff;
#pragma unroll
        for (int j = 0; j < 4; j++) {
            const bool avail = ((selmask >> j) & 1) == 0;
            if (avail && v[j] > bv) { bv = v[j]; bi = lane * 4 + j; }
        }
#pragma unroll
        for (int s = 1; s < 64; s <<= 1) {
            const float ov = __shfl_xor(bv, s, 64);
            const int   oi = __shfl_xor(bi, s, 64);
            if (ov > bv || (ov == bv && oi < bi)) { bv = ov; bi = oi; }
        }
        const int wl = bi >> 2, wj = bi & 3;
        const float mysc = (wj == 0) ? sc[0] : (wj == 1) ? sc[1]
                         : (wj == 2) ? sc[2] : sc[3];
        sum += __shfl(mysc, wl, 64);
        if (lane == wl) selmask |= (1 << wj);
    }

    const float rcp = SCALE / (sum + 1e-20f);
    float4 o;
    o.x = (selmask & 1) ? sc[0] * rcp : 0.0f;
    o.y = (selmask & 2) ? sc[1] * rcp : 0.0f;
    o.z = (selmask & 4) ? sc[2] * rcp : 0.0f;
    o.w = (selmask & 8) ? sc[3] * rcp : 0.0f;
    *(float4*)&S[(size_t)t * NEXPERT + lane * 4] = o;
}

extern "C" void kernel_launch(void* const* d_in, const int* in_sizes, int n_in,
                              void* d_out, int out_size, void* d_ws, size_t ws_size,
                              hipStream_t stream) {
    const float* X    = (const float*)d_in[0];   // [8192, 7168]
    const float* W    = (const float*)d_in[1];   // [256, 7168]
    const float* bias = (const float*)d_in[2];   // [256]
    float* out = (float*)d_out;                  // [8192, 256]
    // d_ws: 448 tiles x 16 KB = 7,340,032 B of pre-split W images. The
    // harness poison-fills d_ws every iteration REGARDLESS of use (R0 vs R1:
    // identical 917 MB fill dispatch) -> using it is free; we rewrite our
    // 7.34 MB slice before the GEMM reads it.
    char* ws = (char*)d_ws; (void)ws_size;

    zero_kernel<<<(TOKENS * NEXPERT / 4) / 256, 256, 0, stream>>>(out);
    wsplit_kernel<<<NEXPERT, 896, 0, stream>>>(W, ws);
    dim3 ggrid(NEXPERT / BN, TOKENS / BM, KSPLIT);   // (2, 64, 4) = 512 blocks
    gate_gemm_kernel<<<ggrid, 256, 0, stream>>>(X, ws, out);
    route_kernel<<<TOKENS / 4, 256, 0, stream>>>(out, bias);
}